// Round 1
// baseline (56.183 us; speedup 1.0000x reference)
//
#include <hip/hip_runtime.h>

#define WL 512   // window_len (t and o dims)
#define NV 64    // n_var
#define LR 16    // low rank
#define NB 512   // batch

__device__ __forceinline__ float tanh_fast(float x) {
    // tanh(x) = 1 - 2/(exp(2x)+1); exact at +-inf saturation, ~1e-7 abs err
    float e = __expf(2.0f * x);
    return 1.0f - 2.0f / (e + 1.0f);
}

// K1: tmp[b,k,v] = sum_t tanh(g[v]*x[b,t,v]) * A[t,k]
// grid = 512 (one block per b), block = 512 threads (8 waves)
// thread: v = tid&63, t-group tg = tid>>6 owns t = tg*64 .. tg*64+63
// Software-pipelined x loads (chunk=8, one chunk lookahead) to hide HBM latency.
// launch_bounds(512,4): VGPR<=128 -> 2 blocks/CU (16 waves/CU), 512 blocks = 1 round.
__global__ __launch_bounds__(512, 4) void k_tmp(
    const float* __restrict__ x, const float* __restrict__ gating,
    const float* __restrict__ A, float* __restrict__ tmp)
{
    __shared__ float A_lds[WL * LR];    // 32 KiB
    __shared__ float red[8 * LR * NV];  // 32 KiB
    const int tid = threadIdx.x;
    const int b = blockIdx.x;

    // stage A: thread tid loads row t=tid (16 floats = 4x float4), coalesced
    {
        const float4* src = (const float4*)(A + tid * LR);
        float4* dst = (float4*)(A_lds + tid * LR);
        dst[0] = src[0]; dst[1] = src[1]; dst[2] = src[2]; dst[3] = src[3];
    }
    __syncthreads();

    const int v = tid & 63;
    const int tg = tid >> 6;
    const float g = gating[v];
    float acc[LR];
#pragma unroll
    for (int k = 0; k < LR; ++k) acc[k] = 0.f;

    const float* xb = x + (size_t)b * (WL * NV) + (size_t)(tg * 64) * NV + v;

    float cur[8], nxt[8];
#pragma unroll
    for (int i = 0; i < 8; ++i) cur[i] = xb[i * NV];   // prefetch chunk 0

    for (int c = 0; c < 64; c += 8) {
        if (c + 8 < 64) {
#pragma unroll
            for (int i = 0; i < 8; ++i) nxt[i] = xb[(c + 8 + i) * NV];  // lookahead
        }
#pragma unroll
        for (int i = 0; i < 8; ++i) {
            const float x1 = tanh_fast(g * cur[i]);
            const float* Ar = &A_lds[(tg * 64 + c + i) * LR];  // wave-uniform -> broadcast
#pragma unroll
            for (int k = 0; k < LR; ++k) acc[k] += x1 * Ar[k];
        }
        if (c + 8 < 64) {
#pragma unroll
            for (int i = 0; i < 8; ++i) cur[i] = nxt[i];
        }
    }

    // reduce the 8 t-group partials via LDS
#pragma unroll
    for (int k = 0; k < LR; ++k) red[(tg * LR + k) * NV + v] = acc[k];
    __syncthreads();
#pragma unroll
    for (int p = tid; p < LR * NV; p += 512) {   // 1024 (k,v) pairs, 2/thread
        float s = 0.f;
#pragma unroll
        for (int t = 0; t < 8; ++t) s += red[t * (LR * NV) + p];
        tmp[(size_t)b * (LR * NV) + p] = s;
    }
}

// K2: out[b,o,v] = x[b,o,v] + bias[o,v] + sum_k tmp[b,k,v]*B[k,o,v]
// grid = (32 b-chunks of 16) x (32 o-tiles of 16), block = 256 (4 waves)
// thread: v = tid&63, wave og = tid>>6 owns o = oTile*16 + og*4 + j, j=0..3
// B slice held in registers (64 VGPR), reused across 16 batches.
// tr (tmp slice) is prefetched one batch ahead; x loads issued before tr-next.
// x loads and out stores are nontemporal (last touch) to keep B/tmp/bias in L2.
__global__ __launch_bounds__(256, 4) void k_out(
    const float* __restrict__ x, const float* __restrict__ bias,
    const float* __restrict__ Bm, const float* __restrict__ tmp,
    float* __restrict__ out)
{
    const int tid = threadIdx.x;
    const int v = tid & 63;
    const int og = tid >> 6;
    const int o_base = blockIdx.y * 16 + og * 4;
    const int b0 = blockIdx.x * 16;

    float Breg[4][LR];
#pragma unroll
    for (int j = 0; j < 4; ++j) {
        const int o = o_base + j;
#pragma unroll
        for (int k = 0; k < LR; ++k)
            Breg[j][k] = Bm[((size_t)k * WL + o) * NV + v];  // 256B/wave, coalesced, L2
    }
    float breg[4];
#pragma unroll
    for (int j = 0; j < 4; ++j) breg[j] = bias[(o_base + j) * NV + v];

    float tr[LR], trn[LR];
    {
        const float* tb = tmp + (size_t)b0 * (LR * NV) + v;
#pragma unroll
        for (int k = 0; k < LR; ++k) tr[k] = tb[k * NV];     // prefetch b0
    }

    for (int bi = 0; bi < 16; ++bi) {
        const int b = b0 + bi;
        const float* xb = x + (size_t)b * WL * NV;
        float* ob = out + (size_t)b * WL * NV;

        // issue x loads early (independent of tr)
        float xr[4];
#pragma unroll
        for (int j = 0; j < 4; ++j)
            xr[j] = __builtin_nontemporal_load(&xb[(o_base + j) * NV + v]);

        // prefetch next batch's tmp slice while we compute this one
        if (bi < 15) {
            const float* tbn = tmp + (size_t)(b + 1) * (LR * NV) + v;
#pragma unroll
            for (int k = 0; k < LR; ++k) trn[k] = tbn[k * NV];
        }

#pragma unroll
        for (int j = 0; j < 4; ++j) {
            float acc = breg[j];
#pragma unroll
            for (int k = 0; k < LR; ++k) acc += tr[k] * Breg[j][k];
            __builtin_nontemporal_store(xr[j] + acc, &ob[(o_base + j) * NV + v]);
        }

        if (bi < 15) {
#pragma unroll
            for (int k = 0; k < LR; ++k) tr[k] = trn[k];
        }
    }
}

extern "C" void kernel_launch(void* const* d_in, const int* in_sizes, int n_in,
                              void* d_out, int out_size, void* d_ws, size_t ws_size,
                              hipStream_t stream) {
    const float* x      = (const float*)d_in[0];  // [512,512,64,1]
    const float* gating = (const float*)d_in[1];  // [64]
    const float* bias   = (const float*)d_in[2];  // [512,64]
    const float* A      = (const float*)d_in[3];  // [512,16]
    const float* Bm     = (const float*)d_in[4];  // [16,512,64]
    float* out = (float*)d_out;
    float* tmp = (float*)d_ws;                    // 512*16*64 f32 = 2 MiB scratch

    k_tmp<<<NB, 512, 0, stream>>>(x, gating, A, tmp);
    k_out<<<dim3(32, 32), 256, 0, stream>>>(x, bias, Bm, tmp, out);
}

// Round 2
// 48.809 us; speedup vs baseline: 1.1511x; 1.1511x over previous
//
#include <hip/hip_runtime.h>

#define WL 512   // window_len (t and o dims)
#define NV 64    // n_var
#define LR 16    // low rank
#define NB 512   // batch

__device__ __forceinline__ float tanh_fast(float x) {
    // tanh(x) = 1 - 2/(exp(2x)+1); exact at +-inf saturation, ~1e-7 abs err
    float e = __expf(2.0f * x);
    return 1.0f - 2.0f / (e + 1.0f);
}

// K1: tmp[b,k,v] = sum_t tanh(g[v]*x[b,t,v]) * A[t,k]
// grid = 512 (one block per b), block = 512 threads (8 waves)
// thread: v = tid&63, t-group tg = tid>>6 owns t = tg*64 .. tg*64+63
// A rows are read via wave-uniform addresses (readfirstlane-forced) so the
// compiler scalarizes them to s_load_dwordx16 and feeds FMAs from SGPRs —
// zero LDS-pipe traffic in the hot loop (the old A_lds broadcast reads were
// ~4 ds_read_b128 per iteration = the real K1 bottleneck).
__global__ __launch_bounds__(512, 4) void k_tmp(
    const float* __restrict__ x, const float* __restrict__ gating,
    const float* __restrict__ A, float* __restrict__ tmp)
{
    __shared__ float red[8 * LR * NV];  // 32 KiB (reduction buffer only)
    const int tid = threadIdx.x;
    const int b = blockIdx.x;

    const int v = tid & 63;
    // tid>>6 is constant across each 64-lane wave; force uniformity so the
    // A loads below become scalar (s_load) instead of vector/LDS ops.
    const int tg = __builtin_amdgcn_readfirstlane(tid >> 6);
    const float g = gating[v];

    float acc[LR];
#pragma unroll
    for (int k = 0; k < LR; ++k) acc[k] = 0.f;

    const float* xb = x + (size_t)b * (WL * NV) + (size_t)tg * 64 * NV + v;
    const float* Abase = A + (size_t)tg * 64 * LR;

#pragma unroll 4
    for (int i = 0; i < 64; ++i) {
        const float x1 = tanh_fast(g * xb[i * NV]);      // 256B/wave, coalesced
        const float* Ar = Abase + i * LR;                // wave-uniform -> s_load
#pragma unroll
        for (int k = 0; k < LR; ++k) acc[k] = fmaf(x1, Ar[k], acc[k]);
    }

    // reduce the 8 t-group partials via LDS (one-time, cheap)
#pragma unroll
    for (int k = 0; k < LR; ++k) red[(tg * LR + k) * NV + v] = acc[k];
    __syncthreads();
#pragma unroll
    for (int p = tid; p < LR * NV; p += 512) {   // 1024 (k,v) pairs, 2/thread
        float s = 0.f;
#pragma unroll
        for (int t = 0; t < 8; ++t) s += red[t * (LR * NV) + p];
        tmp[(size_t)b * (LR * NV) + p] = s;
    }
}

// K2: out[b,o,v] = x[b,o,v] + bias[o,v] + sum_k tmp[b,k,v]*B[k,o,v]
// grid = (64 b-chunks of 8) x (32 o-tiles of 16), block = 256 (4 waves)
// thread: v = tid&63, wave og = tid>>6 owns o = oTile*16 + og*4 + j, j=0..3
// B slice held in registers (64 VGPR) and reused across the 8 batches.
// (exact revert to the verified 52.0 us baseline version)
__global__ __launch_bounds__(256, 4) void k_out(
    const float* __restrict__ x, const float* __restrict__ bias,
    const float* __restrict__ Bm, const float* __restrict__ tmp,
    float* __restrict__ out)
{
    const int tid = threadIdx.x;
    const int v = tid & 63;
    const int og = tid >> 6;
    const int o_base = blockIdx.y * 16 + og * 4;
    const int b0 = blockIdx.x * 8;

    float Breg[4][LR];
#pragma unroll
    for (int j = 0; j < 4; ++j) {
        const int o = o_base + j;
#pragma unroll
        for (int k = 0; k < LR; ++k)
            Breg[j][k] = Bm[((size_t)k * WL + o) * NV + v];  // 256B/wave, coalesced
    }
    float breg[4];
#pragma unroll
    for (int j = 0; j < 4; ++j) breg[j] = bias[(o_base + j) * NV + v];

    for (int bi = 0; bi < 8; ++bi) {
        const int b = b0 + bi;
        const float* tb = tmp + (size_t)b * (LR * NV) + v;
        float tr[LR];
#pragma unroll
        for (int k = 0; k < LR; ++k) tr[k] = tb[k * NV];     // L1/L2-resident
        const float* xb = x + (size_t)b * WL * NV;
        float* ob = out + (size_t)b * WL * NV;
#pragma unroll
        for (int j = 0; j < 4; ++j) {
            const int o = o_base + j;
            float acc = breg[j];
#pragma unroll
            for (int k = 0; k < LR; ++k) acc += tr[k] * Breg[j][k];
            ob[o * NV + v] = xb[o * NV + v] + acc;
        }
    }
}

extern "C" void kernel_launch(void* const* d_in, const int* in_sizes, int n_in,
                              void* d_out, int out_size, void* d_ws, size_t ws_size,
                              hipStream_t stream) {
    const float* x      = (const float*)d_in[0];  // [512,512,64,1]
    const float* gating = (const float*)d_in[1];  // [64]
    const float* bias   = (const float*)d_in[2];  // [512,64]
    const float* A      = (const float*)d_in[3];  // [512,16]
    const float* Bm     = (const float*)d_in[4];  // [16,512,64]
    float* out = (float*)d_out;
    float* tmp = (float*)d_ws;                    // 512*16*64 f32 = 2 MiB scratch

    k_tmp<<<NB, 512, 0, stream>>>(x, gating, A, tmp);
    k_out<<<dim3(64, 32), 256, 0, stream>>>(x, bias, Bm, tmp, out);
}